// Round 4
// baseline (496.537 us; speedup 1.0000x reference)
//
#include <hip/hip_runtime.h>
#include <hip/hip_cooperative_groups.h>

namespace cg = cooperative_groups;

// EGAttention fused single cooperative kernel.
// B=4,H=128,W=128,C=256,NH=8,HD=32. 512 windows x 8 heads.
// 256 blocks x 1024 threads: each block = two window-groups of 8 waves.
// Per (window, head): stage K,V bf16 -> LDS; QK^T MFMA (B-frags via ds_read_b128),
// analytic RPE bias, row norms via quad shuffles, P=1-cos -> per-wave LDS -> PV MFMA,
// xu -> out. Window |S| sums -> part[w]; grid.sync(); redundant 512-way max -> M;
// in-place finalize out = xu*M + res*(1-M)  (xu re-read is same-block, L2-hot).

typedef __attribute__((ext_vector_type(8))) short bf16x8;
typedef __attribute__((ext_vector_type(4))) float f32x4;

#define PI_F 3.14159265358979323846f

__device__ __forceinline__ short f2bf(float f) {
    union { float f; unsigned u; } v; v.f = f;
    unsigned r = v.u + 0x7fffu + ((v.u >> 16) & 1u);   // RNE bf16 (inputs finite)
    return (short)(r >> 16);
}

__device__ __forceinline__ bf16x8 load_frag8(const float* __restrict__ p) {
    float4 x0 = *(const float4*)p;
    float4 x1 = *(const float4*)(p + 4);
    bf16x8 r;
    r[0] = f2bf(x0.x); r[1] = f2bf(x0.y); r[2] = f2bf(x0.z); r[3] = f2bf(x0.w);
    r[4] = f2bf(x1.x); r[5] = f2bf(x1.y); r[6] = f2bf(x1.z); r[7] = f2bf(x1.w);
    return r;
}

__global__ __launch_bounds__(1024, 4) void eg_fused(
    const float* __restrict__ q, const float* __restrict__ k,
    const float* __restrict__ v, const float* __restrict__ res,
    float* __restrict__ out, float* __restrict__ part)
{
    const int t = threadIdx.x;           // 0..1023
    const int wg = t >> 9;               // window group 0/1
    const int lt = t & 511;              // thread within group
    const int w = blockIdx.x * 2 + wg;   // window 0..511
    const int wvg = t >> 6;              // global wave 0..15
    const int wvl = wvg & 7;             // wave within group
    const int lane = t & 63, quad = lane >> 4, l15 = lane & 15;
    const int m0 = wvl * 16;             // wave's 16 rows

    __shared__ __align__(16) short vt[2][32 * 136];   // V^T bf16 [d][j]
    __shared__ __align__(16) short kt[2][128 * 40];   // K bf16 [j][c]
    __shared__ __align__(16) short pw[16][16 * 40];   // per-wave P chunk
    __shared__ float red[2][8];
    __shared__ float gred[16];
    __shared__ float gmax_s;

    // hoisted sin/cos for analytic bias: bias = cb*sin((j-i)*pi/127)
    const float th = PI_F / 127.0f;
    float si[4], ci[4], sj[8], cj[8];
#pragma unroll
    for (int r = 0; r < 4; r++)
        __sincosf((float)(m0 + quad * 4 + r) * th, &si[r], &ci[r]);
#pragma unroll
    for (int tj = 0; tj < 8; tj++)
        __sincosf((float)(tj * 16 + l15) * th, &sj[tj], &cj[tj]);
    const float cb = 0.2f * __sinf((float)(w & 127) * (PI_F / 128.0f));

    const size_t wbase = (size_t)w * 32768;   // w*128*256
    float lsum_tot = 0.f;
    short* pwm = pw[wvg];
    short* vtg = vt[wg];
    short* ktg = kt[wg];

    const int sj_row = lt & 127, sdh = lt >> 7;       // staging: row, chan-quad (0..3)

    for (int n = 0; n < 8; n++) {
        const float* qb = q + wbase + n * 32;
        const float* kb = k + wbase + n * 32;
        const float* vb = v + wbase + n * 32;

        __syncthreads();   // previous tile's LDS readers done

        // ---- stage V^T and K (bf16) into LDS: 512 threads per group ----
        {
            const float* vp = vb + (size_t)sj_row * 256 + sdh * 8;
            const float* kp = kb + (size_t)sj_row * 256 + sdh * 8;
            float4 a0 = ((const float4*)vp)[0];
            float4 a1 = ((const float4*)vp)[1];
            bf16x8 kv = load_frag8(kp);
            float tmp[8] = {a0.x, a0.y, a0.z, a0.w, a1.x, a1.y, a1.z, a1.w};
#pragma unroll
            for (int e = 0; e < 8; e++)
                vtg[(sdh * 8 + e) * 136 + sj_row] = f2bf(tmp[e]);
            *(bf16x8*)&ktg[sj_row * 40 + sdh * 8] = kv;   // contiguous b128
        }

        // Q fragment for this wave's 16 rows (global, unique per wave)
        bf16x8 aq = load_frag8(qb + (size_t)(m0 + l15) * 256 + quad * 8);

        __syncthreads();   // vt/kt ready

        // ---- QK^T: B-fragments from LDS ----
        f32x4 acc[8];
#pragma unroll
        for (int tj = 0; tj < 8; tj++) {
            bf16x8 bk = *(const bf16x8*)&ktg[(tj * 16 + l15) * 40 + quad * 8];
            f32x4 z = {0.f, 0.f, 0.f, 0.f};
            acc[tj] = __builtin_amdgcn_mfma_f32_16x16x32_bf16(aq, bk, z, 0, 0, 0);
        }

        // ---- bias + row sum-sq + window |S| sum ----
        float ss[4] = {0.f, 0.f, 0.f, 0.f};
#pragma unroll
        for (int tj = 0; tj < 8; tj++)
#pragma unroll
            for (int r = 0; r < 4; r++) {
                const float val = acc[tj][r] + cb * (sj[tj] * ci[r] - cj[tj] * si[r]);
                acc[tj][r] = val;
                ss[r] += val * val;
                lsum_tot += fabsf(val);
            }
        float rs[4];
#pragma unroll
        for (int r = 0; r < 4; r++) {
            float s = ss[r];
            s += __shfl_xor(s, 1);
            s += __shfl_xor(s, 2);
            s += __shfl_xor(s, 4);
            s += __shfl_xor(s, 8);
            rs[r] = 1.57079632679f / fmaxf(sqrtf(s), 1e-12f);
        }

        // ---- P = 1-cos -> per-wave LDS -> PV MFMA ----
        f32x4 xacc[2];
        {
            f32x4 z = {0.f, 0.f, 0.f, 0.f};
            xacc[0] = z; xacc[1] = z;
        }
#pragma unroll
        for (int kk = 0; kk < 4; kk++) {
#pragma unroll
            for (int tjl = 0; tjl < 2; tjl++) {
                const int tj = kk * 2 + tjl;
#pragma unroll
                for (int r = 0; r < 4; r++) {
                    const float p = 1.0f - __cosf(acc[tj][r] * rs[r]);
                    pwm[(quad * 4 + r) * 40 + tjl * 16 + l15] = f2bf(p);
                }
            }
            // intra-wave LDS RAW: DS pipe in-order per wave, no barrier needed
            bf16x8 pa = *(const bf16x8*)&pwm[l15 * 40 + quad * 8];
#pragma unroll
            for (int tn = 0; tn < 2; tn++) {
                bf16x8 vf = *(const bf16x8*)&vtg[(tn * 16 + l15) * 136 + kk * 32 + quad * 8];
                xacc[tn] = __builtin_amdgcn_mfma_f32_16x16x32_bf16(pa, vf, xacc[tn], 0, 0, 0);
            }
        }

        // ---- store ungated xu into out ----
        float* ob = out + wbase + n * 32;
#pragma unroll
        for (int tn = 0; tn < 2; tn++)
#pragma unroll
            for (int r = 0; r < 4; r++)
                ob[(size_t)(m0 + quad * 4 + r) * 256 + tn * 16 + l15] = xacc[tn][r];
    }

    // ---- window |S| sum -> part[w] ----
#pragma unroll
    for (int mask = 1; mask < 64; mask <<= 1) lsum_tot += __shfl_xor(lsum_tot, mask);
    if (lane == 0) red[wg][wvl] = lsum_tot;
    __syncthreads();
    if (lt == 0) {
        float s = 0.f;
#pragma unroll
        for (int i = 0; i < 8; i++) s += red[wg][i];
        __hip_atomic_store(&part[w], s, __ATOMIC_RELAXED, __HIP_MEMORY_SCOPE_AGENT);
    }
    __threadfence();

    cg::this_grid().sync();

    // ---- gate: global max of 512 window sums (redundant per block) ----
    float mx = __hip_atomic_load(&part[t & 511], __ATOMIC_RELAXED, __HIP_MEMORY_SCOPE_AGENT);
#pragma unroll
    for (int mask = 1; mask < 64; mask <<= 1) mx = fmaxf(mx, __shfl_xor(mx, mask));
    if (lane == 0) gred[wvg] = mx;
    __syncthreads();
    if (t == 0) {
        float g = gred[0];
#pragma unroll
        for (int i = 1; i < 16; i++) g = fmaxf(g, gred[i]);
        gmax_s = g;
    }
    __syncthreads();
    const float gmax = gmax_s;
    const float own = __hip_atomic_load(&part[w], __ATOMIC_RELAXED, __HIP_MEMORY_SCOPE_AGENT);
    const float Mw = fmaxf(own / gmax, 0.5f);
    const float om = 1.0f - Mw;

    // ---- finalize in place: out = xu*M + res*(1-M) (xu = own group's writes) ----
#pragma unroll
    for (int it = 0; it < 16; it++) {
        const size_t idx = wbase + (size_t)it * 2048 + (size_t)lt * 4;
        float4 xv = *(const float4*)(out + idx);
        float4 rv = *(const float4*)(res + idx);
        float4 o;
        o.x = xv.x * Mw + rv.x * om;
        o.y = xv.y * Mw + rv.y * om;
        o.z = xv.z * Mw + rv.z * om;
        o.w = xv.w * Mw + rv.w * om;
        *(float4*)(out + idx) = o;
    }
}

extern "C" void kernel_launch(void* const* d_in, const int* in_sizes, int n_in,
                              void* d_out, int out_size, void* d_ws, size_t ws_size,
                              hipStream_t stream) {
    const float* qkv = (const float*)d_in[0];
    const float* res = (const float*)d_in[1];
    const long plane = 16777216L;               // B*HW*C
    const float* q = qkv;
    const float* k = qkv + plane;
    const float* v = qkv + 2 * plane;
    float* out = (float*)d_out;
    float* part = (float*)d_ws;                 // 512 floats

    void* args[] = {(void*)&q, (void*)&k, (void*)&v, (void*)&res,
                    (void*)&out, (void*)&part};
    hipLaunchCooperativeKernel((void*)eg_fused, dim3(256), dim3(1024),
                               args, 0, stream);
}